// Round 17
// baseline (210.346 us; speedup 1.0000x reference)
//
#include <hip/hip_runtime.h>
#include <hip/hip_bf16.h>
#include <math.h>

#define B_ 8
#define N_ 8192
#define D_ 512
#define G_ 64
#define M_ (B_ * N_)   // 65536

typedef short bf16x8 __attribute__((ext_vector_type(8)));
typedef float f32x4 __attribute__((ext_vector_type(4)));

__device__ __forceinline__ unsigned short f2bf(float f) {
    __hip_bfloat16 h = __float2bfloat16(f);
    return *reinterpret_cast<unsigned short*>(&h);
}
__device__ __forceinline__ void gload_lds16(const void* g, void* l) {
    __builtin_amdgcn_global_load_lds((const __attribute__((address_space(1))) void*)g,
                                     (__attribute__((address_space(3))) void*)l,
                                     16, 0, 0);
}

// ---------------- merged list build: hist + prefix + emit in one kernel -----
__global__ __launch_bounds__(256) void bl_all(const int* __restrict__ ids,
                                              int* __restrict__ counts,
                                              int* __restrict__ baseO,
                                              int* __restrict__ fgO,
                                              int* __restrict__ perm) {
    __shared__ int sid[N_];                    // 32 KB
    __shared__ unsigned short hist[256][G_];   // 32 KB
    __shared__ int sb[G_ + 1];
    __shared__ int cnts[G_];
    const int g = blockIdx.x;
    const int t = threadIdx.x;
    for (int i = t; i < N_; i += 256) sid[i] = ids[i];
#pragma unroll
    for (int gg = 0; gg < G_; ++gg) hist[t][gg] = 0;
    __syncthreads();
    const int nb = t * 32;
    for (int k = 0; k < 32; ++k) hist[t][sid[nb + k]]++;
    __syncthreads();
    if (t < G_) {      // column prefix over strips for group t
        int run = 0;
        for (int i = 0; i < 256; ++i) {
            int v = hist[i][t];
            hist[i][t] = (unsigned short)run;
            run += v;
        }
        cnts[t] = run;
    }
    __syncthreads();
    if (t == 0) {
        int a = 0;
        for (int gg = 0; gg < G_; ++gg) { sb[gg] = a; a += cnts[gg]; }
        sb[G_] = a;
    }
    __syncthreads();
    if (g == 0 && t < G_) {
        counts[t] = cnts[t];
        baseO[t] = sb[t];
        const int row = t * 128;
        int gg = 0;
        while (gg + 1 < G_ && sb[gg + 1] <= row) ++gg;
        fgO[t] = gg;
    }
    int pos = sb[g] + hist[t][g];
    for (int k = 0; k < 32; ++k)
        if (sid[nb + k] == g) perm[pos++] = nb + k;
}

// ---------------- merged cast: blocks 0..511 = weights, 512..2559 = x -------
__global__ __launch_bounds__(256) void cast_all(const float* __restrict__ x,
                                                const int* __restrict__ perm,
                                                const float* __restrict__ w1,
                                                const float* __restrict__ b1,
                                                const float* __restrict__ w2,
                                                const float* __restrict__ b2,
                                                unsigned short* __restrict__ xb,
                                                unsigned short* __restrict__ wB,
                                                float* __restrict__ biasB) {
    const int bid = blockIdx.x;
    if (bid < 512) {                       // weight cast
        int t = bid * 256 + threadIdx.x;   // one float4
        int idx = t * 4;
        int row = idx >> 9;
        int col = idx & 511;
        const float* src = (row < 512) ? (w1 + (size_t)row * 512 + col)
                                       : (w2 + (size_t)(row - 512) * 512 + col);
        float4 f = *(const float4*)src;
        ushort4 u;
        u.x = f2bf(f.x); u.y = f2bf(f.y); u.z = f2bf(f.z); u.w = f2bf(f.w);
        *(ushort4*)(wB + idx) = u;
        if (t < 1024) biasB[t] = (t < 512) ? b1[t] : b2[t - 512];
    } else {                               // permuted x cast
        const int total = M_ * 128;        // one float4 per item
        for (int idx = (bid - 512) * 256 + threadIdx.x; idx < total;
             idx += 2048 * 256) {
            const int row = idx >> 7;      // b*8192 + permuted slot
            const int q = (idx & 127) * 4;
            const int b = row >> 13;
            const int i = row & 8191;
            const float* src = x + (((size_t)(b << 13) + perm[i]) << 9) + q;
            float4 f = *(const float4*)src;
            ushort4 u;
            u.x = f2bf(f.x); u.y = f2bf(f.y); u.z = f2bf(f.z); u.w = f2bf(f.w);
            *(ushort4*)(xb + ((size_t)row << 9) + q) = u;
        }
    }
}

// ---------------- fused 256x256 MFMA GEMM + segment softmax-aggregate -------
// R12 geometry, SINGLE-buffered LDS (64 KB -> 2 blocks/CU): cross-block
// wave overlap (m114/m97 mechanism) hides the staging drain that the 128KB
// 1-block/CU double-buffer could not. Addressing/swizzle/MFMA order
// bitwise-identical to R12; only the buffering changed.
__global__ __launch_bounds__(512, 2) void gemm_fused(const unsigned short* __restrict__ xb,
                                                     const unsigned short* __restrict__ wB,
                                                     const float* __restrict__ biasB,
                                                     const int* __restrict__ base,
                                                     const int* __restrict__ fg,
                                                     float* __restrict__ pt) {
    extern __shared__ unsigned short smem[];
    unsigned short* lsA = smem;             // [256*64]  32 KB
    unsigned short* lsB = smem + 16384;     // [256*64]  32 KB

    const int o  = blockIdx.x;               // 0..1023
    const int mt = (o & 7) + ((o >> 5) << 3);   // 0..255
    const int nt = (o >> 3) & 3;                // 0..3
    const int b  = mt >> 5;                     // batch
    const int tlb = (mt & 31) * 2;              // first 128-row tile of block
    const int c0 = nt * 128;                    // a/v col base

    const int tid = threadIdx.x;
    const int l = tid & 63;
    const int w = tid >> 6;               // wave 0..7
    const int wm = w >> 2;                // 0..1  (row half)
    const int wn = w & 3;                 // 0..3  (col quarter)
    const int lr = l >> 3;                // staging row-in-chunk
    const int lslot = l & 7;
    const int fr = l & 15;
    const int kq = l >> 4;                // 0..3
    const int scol = 8 * (lslot ^ lr);    // pre-swizzled source col (elems)

    f32x4 acc[8][4];
#pragma unroll
    for (int i = 0; i < 8; ++i)
#pragma unroll
        for (int j = 0; j < 4; ++j) acc[i][j] = (f32x4){0.f, 0.f, 0.f, 0.f};

    const size_t abase = (((size_t)b << 13) + (size_t)(mt & 31) * 256) << 9;

    auto stageT = [&](int kt) {
#pragma unroll
        for (int q = 0; q < 4; ++q) {              // A: 32 chunks of 8 rows
            const int c = w * 4 + q;
            const int row = c * 8 + lr;
            gload_lds16(xb + abase + ((size_t)row << 9) + kt + scol,
                        lsA + c * 512);
        }
#pragma unroll
        for (int q = 0; q < 4; ++q) {              // B: 32 chunks of 8 rows
            const int c = w * 4 + q;
            const int srcrow = ((c >> 2) & 1) * 512 + c0 + (c >> 3) * 32
                             + (c & 3) * 8 + lr;
            gload_lds16(wB + ((size_t)srcrow << 9) + kt + scol,
                        lsB + c * 512);
        }
    };

    for (int t8 = 0; t8 < 8; ++t8) {
        stageT(t8 * 64);
        __syncthreads();     // drains vmcnt -> LDS tile valid
        const int ib0 = 8 * (kq ^ (fr & 7));            // ks=0 swizzled elems
        const int ib1 = 8 * ((4 + kq) ^ (fr & 7));      // ks=1
        bf16x8 bq0[4], bq1[4];
#pragma unroll
        for (int j = 0; j < 4; ++j) {
            const int brow = (wn * 64 + j * 16 + fr) * 64;
            bq0[j] = *(const bf16x8*)&lsB[brow + ib0];
            bq1[j] = *(const bf16x8*)&lsB[brow + ib1];
        }
#pragma unroll
        for (int i = 0; i < 8; ++i) {
            const int arow = (wm * 128 + i * 16 + fr) * 64;
            bf16x8 a0 = *(const bf16x8*)&lsA[arow + ib0];
            bf16x8 a1 = *(const bf16x8*)&lsA[arow + ib1];
#pragma unroll
            for (int j = 0; j < 4; ++j)
                acc[i][j] = __builtin_amdgcn_mfma_f32_16x16x32_bf16(a0, bq0[j], acc[i][j], 0, 0, 0);
#pragma unroll
            for (int j = 0; j < 4; ++j)
                acc[i][j] = __builtin_amdgcn_mfma_f32_16x16x32_bf16(a1, bq1[j], acc[i][j], 0, 0, 0);
        }
        __syncthreads();     // all reads done before next stage overwrites
    }

    // ---- epilogue: exp + per-wave segment reduce (wave owns full tl) ----
    const int tl = tlb + wm;
    const int fg0 = fg[tl];
    const int bnd0 = (fg0 + 1 < G_) ? base[fg0 + 1] : (1 << 30);
    const int bnd1 = (fg0 + 2 < G_) ? base[fg0 + 2] : (1 << 30);
    const int bnd2 = (fg0 + 3 < G_) ? base[fg0 + 3] : (1 << 30);
    float b1c[2], b2c[2];
#pragma unroll
    for (int j = 0; j < 2; ++j) {
        const int col = c0 + wn * 32 + j * 16 + fr;
        b1c[j] = biasB[col];
        b2c[j] = biasB[512 + col];
    }
    float dp[4][2] = {}, yp[4][2] = {};
    const int rbase = tl * 128 + kq * 4;
#pragma unroll
    for (int i = 0; i < 8; ++i)
#pragma unroll
        for (int rr = 0; rr < 4; ++rr) {
            const int row = rbase + i * 16 + rr;
            const int s = (row >= bnd0) + (row >= bnd1) + (row >= bnd2);
#pragma unroll
            for (int j = 0; j < 2; ++j) {
                const float e = __expf(acc[i][j][rr] + b1c[j]);
                const float ey = e * (acc[i][j + 2][rr] + b2c[j]);
#pragma unroll
                for (int s2 = 0; s2 < 4; ++s2) {
                    dp[s2][j] += (s == s2) ? e : 0.f;
                    yp[s2][j] += (s == s2) ? ey : 0.f;
                }
            }
        }
#pragma unroll
    for (int s2 = 0; s2 < 4; ++s2)
#pragma unroll
        for (int j = 0; j < 2; ++j) {
            dp[s2][j] += __shfl_xor(dp[s2][j], 16);
            dp[s2][j] += __shfl_xor(dp[s2][j], 32);
            yp[s2][j] += __shfl_xor(yp[s2][j], 16);
            yp[s2][j] += __shfl_xor(yp[s2][j], 32);
        }
    if (kq == 0) {
#pragma unroll
        for (int s2 = 0; s2 < 4; ++s2)
#pragma unroll
            for (int j = 0; j < 2; ++j) {
                const int colp = c0 + wn * 32 + j * 16 + fr;
                float2 v = make_float2(dp[s2][j], yp[s2][j]);
                *(float2*)&pt[(((size_t)(b * 64 + tl) * 4 + s2) * 512 + colp) * 2] = v;
            }
    }
}

// ---------------- ordered cross-tile combine -> y[b][g][col] ----------------
__global__ __launch_bounds__(256) void combineC(const float* __restrict__ pt,
                                                const int* __restrict__ base,
                                                const int* __restrict__ counts,
                                                const int* __restrict__ fg,
                                                float* __restrict__ y) {
    const int g = blockIdx.x, b = blockIdx.y;
    const int bs = base[g];
    int cnt = counts[g];
    if (cnt == 0) cnt = 1;
    const int t0 = bs >> 7, t1 = (bs + cnt - 1) >> 7;
    for (int c = threadIdx.x; c < 512; c += 256) {
        float d = 0.f, yy = 0.f;
        for (int t = t0; t <= t1; ++t) {
            const int s = g - fg[t];
            if (s >= 0 && s < 4) {
                const float* p = &pt[((((size_t)(b * 64 + t)) * 4 + s) * 512 + c) * 2];
                d += p[0];
                yy += p[1];
            }
        }
        y[((size_t)(b * G_ + g)) * 512 + c] = yy / d;
    }
}

// ---------------- small GEMM: out_small = y @ w3^T + b3 (f32 vector) --------
__global__ __launch_bounds__(256) void gemm3(const float* __restrict__ y,
                                             const float* __restrict__ w3,
                                             const float* __restrict__ b3,
                                             float* __restrict__ out_small) {
    __shared__ float ys[16][68];
    __shared__ float wss[16][68];
    const int m0 = blockIdx.x * 64;
    const int n0 = blockIdx.y * 64;
    const int tid = threadIdx.x;
    const int tr = tid >> 4;
    const int tc = tid & 15;
    const int lrow = tid >> 2;
    const int lk4 = (tid & 3) * 4;

    float acc[4][4] = {};

    for (int k0 = 0; k0 < D_; k0 += 16) {
        float4 yv = *(const float4*)(y + (size_t)(m0 + lrow) * D_ + k0 + lk4);
        float4 wv = *(const float4*)(w3 + (size_t)(n0 + lrow) * D_ + k0 + lk4);
        __syncthreads();
        ys[lk4 + 0][lrow] = yv.x;  ys[lk4 + 1][lrow] = yv.y;
        ys[lk4 + 2][lrow] = yv.z;  ys[lk4 + 3][lrow] = yv.w;
        wss[lk4 + 0][lrow] = wv.x; wss[lk4 + 1][lrow] = wv.y;
        wss[lk4 + 2][lrow] = wv.z; wss[lk4 + 3][lrow] = wv.w;
        __syncthreads();
#pragma unroll
        for (int kk = 0; kk < 16; ++kk) {
            float4 y4 = *(const float4*)&ys[kk][tr * 4];
            float4 w4 = *(const float4*)&wss[kk][tc * 4];
            float ya[4] = {y4.x, y4.y, y4.z, y4.w};
            float wa[4] = {w4.x, w4.y, w4.z, w4.w};
#pragma unroll
            for (int i = 0; i < 4; ++i)
#pragma unroll
                for (int j = 0; j < 4; ++j)
                    acc[i][j] = fmaf(ya[i], wa[j], acc[i][j]);
        }
    }

    float bb[4];
#pragma unroll
    for (int j = 0; j < 4; ++j) bb[j] = b3[n0 + tc * 4 + j];
#pragma unroll
    for (int i = 0; i < 4; ++i) {
        size_t o = (size_t)(m0 + tr * 4 + i) * D_ + n0 + tc * 4;
        float4 r;
        r.x = acc[i][0] + bb[0]; r.y = acc[i][1] + bb[1];
        r.z = acc[i][2] + bb[2]; r.w = acc[i][3] + bb[3];
        *(float4*)(out_small + o) = r;
    }
}

// ---------------- gather group outputs back to rows -------------------------
__global__ __launch_bounds__(256) void gather_out(const int* __restrict__ ids,
                                                  const float* __restrict__ out_small,
                                                  float* __restrict__ out) {
    const int c = blockIdx.x * 256 + threadIdx.x;   // one float4 chunk
    const int per_row = D_ / 4;                     // 128
    const int b = c / (N_ * per_row);
    const int rem = c % (N_ * per_row);
    const int n = rem / per_row;
    const int q = rem % per_row;
    const int g = ids[n];
    float4 val = *(const float4*)(out_small + ((size_t)b * G_ + g) * D_ + q * 4);
    *(float4*)(out + (size_t)c * 4) = val;
}

// ---------------- launcher --------------------------------------------------
extern "C" void kernel_launch(void* const* d_in, const int* in_sizes, int n_in,
                              void* d_out, int out_size, void* d_ws, size_t ws_size,
                              hipStream_t stream) {
    (void)in_sizes; (void)n_in; (void)out_size; (void)ws_size;
    const float* x   = (const float*)d_in[0];
    const int*   ids = (const int*)d_in[1];
    const float* w1  = (const float*)d_in[2];
    const float* b1  = (const float*)d_in[3];
    const float* w2  = (const float*)d_in[4];
    const float* b2  = (const float*)d_in[5];
    const float* w3  = (const float*)d_in[6];
    const float* b3  = (const float*)d_in[7];
    float* out = (float*)d_out;

    float* ws_f = (float*)d_ws;
    unsigned short* xb = (unsigned short*)ws_f;          // 64 MB (permuted bf16 x)
    float* after_xb  = ws_f + 16777216;
    unsigned short* wB = (unsigned short*)after_xb;      // 1 MB
    float* biasB     = after_xb + 262144;                // 4 KB
    float* pt        = biasB + 1024;                     // 8 MB  [b*64+tl][4][512][2]
    float* y         = pt + 2097152;                     // 1 MB
    float* out_small = y + 262144;                       // 1 MB
    int*   perm      = (int*)(out_small + 262144);       // 32 KB
    int*   base      = perm + N_;
    int*   counts    = base + G_;
    int*   fg        = counts + G_;

    hipFuncSetAttribute((const void*)gemm_fused,
                        hipFuncAttributeMaxDynamicSharedMemorySize, 65536);

    hipLaunchKernelGGL(bl_all, dim3(G_), dim3(256), 0, stream, ids, counts, base, fg, perm);
    hipLaunchKernelGGL(cast_all, dim3(2560), dim3(256), 0, stream,
                       x, perm, w1, b1, w2, b2, xb, wB, biasB);
    hipLaunchKernelGGL(gemm_fused, dim3(1024), dim3(512), 65536, stream,
                       xb, wB, biasB, base, fg, pt);
    hipLaunchKernelGGL(combineC, dim3(G_, B_), dim3(256), 0, stream, pt, base, counts, fg, y);
    hipLaunchKernelGGL(gemm3, dim3(8, 8), dim3(256), 0, stream, y, w3, b3, out_small);
    hipLaunchKernelGGL(gather_out, dim3(32768), dim3(256), 0, stream, ids, out_small, out);
}

// Round 18
// 192.502 us; speedup vs baseline: 1.0927x; 1.0927x over previous
//
#include <hip/hip_runtime.h>
#include <hip/hip_bf16.h>
#include <math.h>

#define B_ 8
#define N_ 8192
#define D_ 512
#define G_ 64
#define M_ (B_ * N_)   // 65536

typedef short bf16x8 __attribute__((ext_vector_type(8)));
typedef float f32x4 __attribute__((ext_vector_type(4)));

__device__ __forceinline__ unsigned short f2bf(float f) {
    __hip_bfloat16 h = __float2bfloat16(f);
    return *reinterpret_cast<unsigned short*>(&h);
}
__device__ __forceinline__ void gload_lds16(const void* g, void* l) {
    __builtin_amdgcn_global_load_lds((const __attribute__((address_space(1))) void*)g,
                                     (__attribute__((address_space(3))) void*)l,
                                     16, 0, 0);
}

// ---------------- merged list build: hist + prefix + emit in one kernel -----
__global__ __launch_bounds__(256) void bl_all(const int* __restrict__ ids,
                                              int* __restrict__ counts,
                                              int* __restrict__ baseO,
                                              int* __restrict__ fgO,
                                              int* __restrict__ perm) {
    __shared__ int sid[N_];                    // 32 KB
    __shared__ unsigned short hist[256][G_];   // 32 KB
    __shared__ int sb[G_ + 1];
    __shared__ int cnts[G_];
    const int g = blockIdx.x;
    const int t = threadIdx.x;
    for (int i = t; i < N_; i += 256) sid[i] = ids[i];
#pragma unroll
    for (int gg = 0; gg < G_; ++gg) hist[t][gg] = 0;
    __syncthreads();
    const int nb = t * 32;
    for (int k = 0; k < 32; ++k) hist[t][sid[nb + k]]++;
    __syncthreads();
    if (t < G_) {      // column prefix over strips for group t
        int run = 0;
        for (int i = 0; i < 256; ++i) {
            int v = hist[i][t];
            hist[i][t] = (unsigned short)run;
            run += v;
        }
        cnts[t] = run;
    }
    __syncthreads();
    if (t == 0) {
        int a = 0;
        for (int gg = 0; gg < G_; ++gg) { sb[gg] = a; a += cnts[gg]; }
        sb[G_] = a;
    }
    __syncthreads();
    if (g == 0 && t < G_) {
        counts[t] = cnts[t];
        baseO[t] = sb[t];
        const int row = t * 128;
        int gg = 0;
        while (gg + 1 < G_ && sb[gg + 1] <= row) ++gg;
        fgO[t] = gg;
    }
    int pos = sb[g] + hist[t][g];
    for (int k = 0; k < 32; ++k)
        if (sid[nb + k] == g) perm[pos++] = nb + k;
}

// ---------------- merged cast: blocks 0..511 = weights, 512..2559 = x -------
__global__ __launch_bounds__(256) void cast_all(const float* __restrict__ x,
                                                const int* __restrict__ perm,
                                                const float* __restrict__ w1,
                                                const float* __restrict__ b1,
                                                const float* __restrict__ w2,
                                                const float* __restrict__ b2,
                                                unsigned short* __restrict__ xb,
                                                unsigned short* __restrict__ wB,
                                                float* __restrict__ biasB) {
    const int bid = blockIdx.x;
    if (bid < 512) {                       // weight cast
        int t = bid * 256 + threadIdx.x;   // one float4
        int idx = t * 4;
        int row = idx >> 9;
        int col = idx & 511;
        const float* src = (row < 512) ? (w1 + (size_t)row * 512 + col)
                                       : (w2 + (size_t)(row - 512) * 512 + col);
        float4 f = *(const float4*)src;
        ushort4 u;
        u.x = f2bf(f.x); u.y = f2bf(f.y); u.z = f2bf(f.z); u.w = f2bf(f.w);
        *(ushort4*)(wB + idx) = u;
        if (t < 1024) biasB[t] = (t < 512) ? b1[t] : b2[t - 512];
    } else {                               // permuted x cast
        const int total = M_ * 128;        // one float4 per item
        for (int idx = (bid - 512) * 256 + threadIdx.x; idx < total;
             idx += 2048 * 256) {
            const int row = idx >> 7;      // b*8192 + permuted slot
            const int q = (idx & 127) * 4;
            const int b = row >> 13;
            const int i = row & 8191;
            const float* src = x + (((size_t)(b << 13) + perm[i]) << 9) + q;
            float4 f = *(const float4*)src;
            ushort4 u;
            u.x = f2bf(f.x); u.y = f2bf(f.y); u.z = f2bf(f.z); u.w = f2bf(f.w);
            *(ushort4*)(xb + ((size_t)row << 9) + q) = u;
        }
    }
}

// ---------------- fused 256x256 MFMA GEMM + segment softmax-aggregate -------
// R9/R12-proven version: BM=256 permuted rows, paired BN = 128 a-cols + 128
// v-cols, BK=64, 8 waves (2x4), 128 KB dynamic LDS full-K-tile double buffer,
// XOR-swizzled staging via global_load_lds + pre-swizzled source cols.
__global__ __launch_bounds__(512, 2) void gemm_fused(const unsigned short* __restrict__ xb,
                                                     const unsigned short* __restrict__ wB,
                                                     const float* __restrict__ biasB,
                                                     const int* __restrict__ base,
                                                     const int* __restrict__ fg,
                                                     float* __restrict__ pt) {
    extern __shared__ unsigned short smem[];
    unsigned short* lsA = smem;             // [2][256*64]  64 KB
    unsigned short* lsB = smem + 32768;     // [2][256*64]  64 KB

    const int o  = blockIdx.x;               // 0..1023
    const int mt = (o & 7) + ((o >> 5) << 3);   // 0..255
    const int nt = (o >> 3) & 3;                // 0..3
    const int b  = mt >> 5;                     // batch
    const int tlb = (mt & 31) * 2;              // first 128-row tile of block
    const int c0 = nt * 128;                    // a/v col base

    const int tid = threadIdx.x;
    const int l = tid & 63;
    const int w = tid >> 6;               // wave 0..7
    const int wm = w >> 2;                // 0..1  (row half)
    const int wn = w & 3;                 // 0..3  (col quarter)
    const int lr = l >> 3;                // staging row-in-chunk
    const int lslot = l & 7;
    const int fr = l & 15;
    const int kq = l >> 4;                // 0..3
    const int scol = 8 * (lslot ^ lr);    // pre-swizzled source col (elems)

    f32x4 acc[8][4];
#pragma unroll
    for (int i = 0; i < 8; ++i)
#pragma unroll
        for (int j = 0; j < 4; ++j) acc[i][j] = (f32x4){0.f, 0.f, 0.f, 0.f};

    const size_t abase = (((size_t)b << 13) + (size_t)(mt & 31) * 256) << 9;

    auto stageT = [&](int buf, int kt) {
#pragma unroll
        for (int q = 0; q < 4; ++q) {              // A: 32 chunks of 8 rows
            const int c = w * 4 + q;
            const int row = c * 8 + lr;
            gload_lds16(xb + abase + ((size_t)row << 9) + kt + scol,
                        lsA + buf * 16384 + c * 512);
        }
#pragma unroll
        for (int q = 0; q < 4; ++q) {              // B: 32 chunks of 8 rows
            const int c = w * 4 + q;
            const int srcrow = ((c >> 2) & 1) * 512 + c0 + (c >> 3) * 32
                             + (c & 3) * 8 + lr;
            gload_lds16(wB + ((size_t)srcrow << 9) + kt + scol,
                        lsB + buf * 16384 + c * 512);
        }
    };

    stageT(0, 0);
    __syncthreads();
    int cur = 0;
    for (int t8 = 0; t8 < 8; ++t8) {
        if (t8 < 7) stageT(cur ^ 1, (t8 + 1) * 64);     // async prefetch
        const unsigned short* pA = lsA + cur * 16384;
        const unsigned short* pB = lsB + cur * 16384;
        const int ib0 = 8 * (kq ^ (fr & 7));            // ks=0 swizzled elems
        const int ib1 = 8 * ((4 + kq) ^ (fr & 7));      // ks=1
        bf16x8 bq0[4], bq1[4];
#pragma unroll
        for (int j = 0; j < 4; ++j) {
            const int brow = (wn * 64 + j * 16 + fr) * 64;
            bq0[j] = *(const bf16x8*)&pB[brow + ib0];
            bq1[j] = *(const bf16x8*)&pB[brow + ib1];
        }
#pragma unroll
        for (int i = 0; i < 8; ++i) {
            const int arow = (wm * 128 + i * 16 + fr) * 64;
            bf16x8 a0 = *(const bf16x8*)&pA[arow + ib0];
            bf16x8 a1 = *(const bf16x8*)&pA[arow + ib1];
#pragma unroll
            for (int j = 0; j < 4; ++j)
                acc[i][j] = __builtin_amdgcn_mfma_f32_16x16x32_bf16(a0, bq0[j], acc[i][j], 0, 0, 0);
#pragma unroll
            for (int j = 0; j < 4; ++j)
                acc[i][j] = __builtin_amdgcn_mfma_f32_16x16x32_bf16(a1, bq1[j], acc[i][j], 0, 0, 0);
        }
        __syncthreads();     // drains ds reads + prefetch vmcnt
        cur ^= 1;
    }

    // ---- epilogue: exp + per-wave segment reduce (wave owns full tl) ----
    const int tl = tlb + wm;
    const int fg0 = fg[tl];
    const int bnd0 = (fg0 + 1 < G_) ? base[fg0 + 1] : (1 << 30);
    const int bnd1 = (fg0 + 2 < G_) ? base[fg0 + 2] : (1 << 30);
    const int bnd2 = (fg0 + 3 < G_) ? base[fg0 + 3] : (1 << 30);
    float b1c[2], b2c[2];
#pragma unroll
    for (int j = 0; j < 2; ++j) {
        const int col = c0 + wn * 32 + j * 16 + fr;
        b1c[j] = biasB[col];
        b2c[j] = biasB[512 + col];
    }
    float dp[4][2] = {}, yp[4][2] = {};
    const int rbase = tl * 128 + kq * 4;
#pragma unroll
    for (int i = 0; i < 8; ++i)
#pragma unroll
        for (int rr = 0; rr < 4; ++rr) {
            const int row = rbase + i * 16 + rr;
            const int s = (row >= bnd0) + (row >= bnd1) + (row >= bnd2);
#pragma unroll
            for (int j = 0; j < 2; ++j) {
                const float e = __expf(acc[i][j][rr] + b1c[j]);
                const float ey = e * (acc[i][j + 2][rr] + b2c[j]);
#pragma unroll
                for (int s2 = 0; s2 < 4; ++s2) {
                    dp[s2][j] += (s == s2) ? e : 0.f;
                    yp[s2][j] += (s == s2) ? ey : 0.f;
                }
            }
        }
#pragma unroll
    for (int s2 = 0; s2 < 4; ++s2)
#pragma unroll
        for (int j = 0; j < 2; ++j) {
            dp[s2][j] += __shfl_xor(dp[s2][j], 16);
            dp[s2][j] += __shfl_xor(dp[s2][j], 32);
            yp[s2][j] += __shfl_xor(yp[s2][j], 16);
            yp[s2][j] += __shfl_xor(yp[s2][j], 32);
        }
    if (kq == 0) {
#pragma unroll
        for (int s2 = 0; s2 < 4; ++s2)
#pragma unroll
            for (int j = 0; j < 2; ++j) {
                const int colp = c0 + wn * 32 + j * 16 + fr;
                float2 v = make_float2(dp[s2][j], yp[s2][j]);
                *(float2*)&pt[(((size_t)(b * 64 + tl) * 4 + s2) * 512 + colp) * 2] = v;
            }
    }
}

// ---------------- ordered cross-tile combine -> y[b][g][col] ----------------
__global__ __launch_bounds__(256) void combineC(const float* __restrict__ pt,
                                                const int* __restrict__ base,
                                                const int* __restrict__ counts,
                                                const int* __restrict__ fg,
                                                float* __restrict__ y) {
    const int g = blockIdx.x, b = blockIdx.y;
    const int bs = base[g];
    int cnt = counts[g];
    if (cnt == 0) cnt = 1;
    const int t0 = bs >> 7, t1 = (bs + cnt - 1) >> 7;
    for (int c = threadIdx.x; c < 512; c += 256) {
        float d = 0.f, yy = 0.f;
        for (int t = t0; t <= t1; ++t) {
            const int s = g - fg[t];
            if (s >= 0 && s < 4) {
                const float* p = &pt[((((size_t)(b * 64 + t)) * 4 + s) * 512 + c) * 2];
                d += p[0];
                yy += p[1];
            }
        }
        y[((size_t)(b * G_ + g)) * 512 + c] = yy / d;
    }
}

// ---------------- small GEMM: out_small = y @ w3^T + b3 (f32 vector) --------
__global__ __launch_bounds__(256) void gemm3(const float* __restrict__ y,
                                             const float* __restrict__ w3,
                                             const float* __restrict__ b3,
                                             float* __restrict__ out_small) {
    __shared__ float ys[16][68];
    __shared__ float wss[16][68];
    const int m0 = blockIdx.x * 64;
    const int n0 = blockIdx.y * 64;
    const int tid = threadIdx.x;
    const int tr = tid >> 4;
    const int tc = tid & 15;
    const int lrow = tid >> 2;
    const int lk4 = (tid & 3) * 4;

    float acc[4][4] = {};

    for (int k0 = 0; k0 < D_; k0 += 16) {
        float4 yv = *(const float4*)(y + (size_t)(m0 + lrow) * D_ + k0 + lk4);
        float4 wv = *(const float4*)(w3 + (size_t)(n0 + lrow) * D_ + k0 + lk4);
        __syncthreads();
        ys[lk4 + 0][lrow] = yv.x;  ys[lk4 + 1][lrow] = yv.y;
        ys[lk4 + 2][lrow] = yv.z;  ys[lk4 + 3][lrow] = yv.w;
        wss[lk4 + 0][lrow] = wv.x; wss[lk4 + 1][lrow] = wv.y;
        wss[lk4 + 2][lrow] = wv.z; wss[lk4 + 3][lrow] = wv.w;
        __syncthreads();
#pragma unroll
        for (int kk = 0; kk < 16; ++kk) {
            float4 y4 = *(const float4*)&ys[kk][tr * 4];
            float4 w4 = *(const float4*)&wss[kk][tc * 4];
            float ya[4] = {y4.x, y4.y, y4.z, y4.w};
            float wa[4] = {w4.x, w4.y, w4.z, w4.w};
#pragma unroll
            for (int i = 0; i < 4; ++i)
#pragma unroll
                for (int j = 0; j < 4; ++j)
                    acc[i][j] = fmaf(ya[i], wa[j], acc[i][j]);
        }
    }

    float bb[4];
#pragma unroll
    for (int j = 0; j < 4; ++j) bb[j] = b3[n0 + tc * 4 + j];
#pragma unroll
    for (int i = 0; i < 4; ++i) {
        size_t o = (size_t)(m0 + tr * 4 + i) * D_ + n0 + tc * 4;
        float4 r;
        r.x = acc[i][0] + bb[0]; r.y = acc[i][1] + bb[1];
        r.z = acc[i][2] + bb[2]; r.w = acc[i][3] + bb[3];
        *(float4*)(out_small + o) = r;
    }
}

// ---------------- gather group outputs back to rows -------------------------
__global__ __launch_bounds__(256) void gather_out(const int* __restrict__ ids,
                                                  const float* __restrict__ out_small,
                                                  float* __restrict__ out) {
    const int c = blockIdx.x * 256 + threadIdx.x;   // one float4 chunk
    const int per_row = D_ / 4;                     // 128
    const int b = c / (N_ * per_row);
    const int rem = c % (N_ * per_row);
    const int n = rem / per_row;
    const int q = rem % per_row;
    const int g = ids[n];
    float4 val = *(const float4*)(out_small + ((size_t)b * G_ + g) * D_ + q * 4);
    *(float4*)(out + (size_t)c * 4) = val;
}

// ---------------- launcher --------------------------------------------------
extern "C" void kernel_launch(void* const* d_in, const int* in_sizes, int n_in,
                              void* d_out, int out_size, void* d_ws, size_t ws_size,
                              hipStream_t stream) {
    (void)in_sizes; (void)n_in; (void)out_size; (void)ws_size;
    const float* x   = (const float*)d_in[0];
    const int*   ids = (const int*)d_in[1];
    const float* w1  = (const float*)d_in[2];
    const float* b1  = (const float*)d_in[3];
    const float* w2  = (const float*)d_in[4];
    const float* b2  = (const float*)d_in[5];
    const float* w3  = (const float*)d_in[6];
    const float* b3  = (const float*)d_in[7];
    float* out = (float*)d_out;

    float* ws_f = (float*)d_ws;
    unsigned short* xb = (unsigned short*)ws_f;          // 64 MB (permuted bf16 x)
    float* after_xb  = ws_f + 16777216;
    unsigned short* wB = (unsigned short*)after_xb;      // 1 MB
    float* biasB     = after_xb + 262144;                // 4 KB
    float* pt        = biasB + 1024;                     // 8 MB  [b*64+tl][4][512][2]
    float* y         = pt + 2097152;                     // 1 MB
    float* out_small = y + 262144;                       // 1 MB
    int*   perm      = (int*)(out_small + 262144);       // 32 KB
    int*   base      = perm + N_;
    int*   counts    = base + G_;
    int*   fg        = counts + G_;

    hipFuncSetAttribute((const void*)gemm_fused,
                        hipFuncAttributeMaxDynamicSharedMemorySize, 131072);

    hipLaunchKernelGGL(bl_all, dim3(G_), dim3(256), 0, stream, ids, counts, base, fg, perm);
    hipLaunchKernelGGL(cast_all, dim3(2560), dim3(256), 0, stream,
                       x, perm, w1, b1, w2, b2, xb, wB, biasB);
    hipLaunchKernelGGL(gemm_fused, dim3(1024), dim3(512), 131072, stream,
                       xb, wB, biasB, base, fg, pt);
    hipLaunchKernelGGL(combineC, dim3(G_, B_), dim3(256), 0, stream, pt, base, counts, fg, y);
    hipLaunchKernelGGL(gemm3, dim3(8, 8), dim3(256), 0, stream, y, w3, b3, out_small);
    hipLaunchKernelGGL(gather_out, dim3(32768), dim3(256), 0, stream, ids, out_small, out);
}